// Round 1
// baseline (482.048 us; speedup 1.0000x reference)
//
#include <hip/hip_runtime.h>

#define VDIM 207
#define LDIM 128
#define VP 224            // padded V (multiple of 16, covers K-steps 7*32)
#define VL (VDIM*LDIM)    // 26496
#define NC 1024           // B*C = 32*32
#define NPOINT (32*VL)    // B*V*L = 847872

typedef unsigned short u16;
typedef unsigned int u32;
typedef __attribute__((ext_vector_type(4))) float f32x4;
typedef __attribute__((ext_vector_type(8))) short s16x8;

__device__ __forceinline__ u16 f2bf(float f) {
  u32 u = __float_as_uint(f);
  return (u16)((u + 0x7FFFu + ((u >> 16) & 1u)) >> 16);  // RNE
}
__device__ __forceinline__ float bf2f(u16 h) {
  return __uint_as_float(((u32)h) << 16);
}

// ---------------- prep: AT[i][w][v] = bf16(A_i[v][w]) zero-padded to 224x224;
//                  WT[k][o] = W[o][k]  (k = 0..223, o = 0..31) ----------------
__global__ void k_prep(const float* __restrict__ A0, const float* __restrict__ A1,
                       const float* __restrict__ A2, const float* __restrict__ W,
                       u16* __restrict__ AT, float* __restrict__ WT) {
  int idx = blockIdx.x * 256 + threadIdx.x;
  if (idx < 3 * VP * VP) {
    int i = idx / (VP * VP);
    int r = idx % (VP * VP);
    int w = r / VP, v = r % VP;
    const float* A = (i == 0) ? A0 : ((i == 1) ? A1 : A2);
    float f = (w < VDIM && v < VDIM) ? A[v * VDIM + w] : 0.f;
    AT[idx] = f2bf(f);
  } else {
    int j = idx - 3 * VP * VP;
    if (j < VP * 32) {
      int k = j >> 5, o = j & 31;
      WT[j] = W[o * 224 + k];
    }
  }
}

// ---------------- transpose x -> xT bf16 [nc][l=128][v=224] ----------------
__global__ __launch_bounds__(256) void k_xt(const float* __restrict__ x,
                                            u16* __restrict__ xT) {
  __shared__ float tile[64 * 130];  // [64 v][128 l] padded stride 130
  int nc = blockIdx.x;
  const float* xs = x + (size_t)nc * VL;
  u16* xd = xT + (size_t)nc * (128 * VP);
  int tid = threadIdx.x;
  for (int ch = 0; ch < 4; ++ch) {
    int v0 = ch * 64;
    __syncthreads();
    // load 64 rows x 128 cols, coalesced float4
#pragma unroll
    for (int j = 0; j < 8; ++j) {
      int idx = j * 256 + tid;        // over [64][32 float4]
      int vr = idx >> 5, c4 = idx & 31;
      int v = v0 + vr;
      float4 val = make_float4(0.f, 0.f, 0.f, 0.f);
      if (v < VDIM) val = *(const float4*)(xs + (size_t)v * LDIM + c4 * 4);
      float* trow = &tile[vr * 130 + c4 * 4];
      *(float2*)(trow) = make_float2(val.x, val.y);
      *(float2*)(trow + 2) = make_float2(val.z, val.w);
    }
    __syncthreads();
    // write transposed: row l, 32 v each
    int l = tid >> 1, h = tid & 1;
    int vbase = v0 + h * 32;
    if (vbase < VP) {
      u32 wd[16];
#pragma unroll
      for (int j = 0; j < 16; ++j) {
        int v = vbase + 2 * j;
        float f0 = (v < VDIM) ? tile[(h * 32 + 2 * j) * 130 + l] : 0.f;
        float f1 = (v + 1 < VDIM) ? tile[(h * 32 + 2 * j + 1) * 130 + l] : 0.f;
        wd[j] = (u32)f2bf(f0) | ((u32)f2bf(f1) << 16);
      }
      uint4* dst = (uint4*)(xd + (size_t)l * VP + vbase);
#pragma unroll
      for (int t = 0; t < 4; ++t)
        dst[t] = make_uint4(wd[4 * t], wd[4 * t + 1], wd[4 * t + 2], wd[4 * t + 3]);
    }
  }
}

// ---------------- fused double-hop: z1 = A^T x, z2 = A^T z1 (per (n,c)) -------
// LDS: xT_s[128][224] bf16 | z1T_s[128][224] bf16 | apan[2][224][40] bf16
__global__ __launch_bounds__(512, 2) void k_hops(const u16* __restrict__ xT,
                                                 const u16* __restrict__ AT,
                                                 u16* __restrict__ zbuf,
                                                 int i0, int icount) {
  __shared__ __align__(16) u16 smem[75264];
  u16* xT_s = smem;             // 28672 u16
  u16* z1T_s = smem + 28672;    // 28672 u16
  u16* apan = smem + 57344;     // 2*8960 u16

  int tid = threadIdx.x;
  int lane = tid & 63, wid = tid >> 6;
  int lane15 = lane & 15, lgrp = lane >> 4;
  int wm = wid >> 2, wn = wid & 3;  // wave grid: 2 (M) x 4 (N)
  int nc = blockIdx.x;

  // stage xT slab (linear 57344 B)
  {
    const uint4* src = (const uint4*)(xT + (size_t)nc * (128 * VP));
    uint4* dst = (uint4*)xT_s;
#pragma unroll
    for (int j = 0; j < 7; ++j) dst[j * 512 + tid] = src[j * 512 + tid];
  }

  int r = tid >> 1, h = tid & 1;  // a_panel staging role: row r, 32B half h

  for (int ii = 0; ii < icount; ++ii) {
    int i = i0 + ii;
    const u16* ATi = AT + i * (VP * VP);
    for (int hop = 0; hop < 2; ++hop) {
      const u16* bsrc = (hop == 0) ? xT_s : z1T_s;
      f32x4 acc[14];
#pragma unroll
      for (int m = 0; m < 14; ++m) acc[m] = (f32x4){0.f, 0.f, 0.f, 0.f};

      // stage a_panel ks=0 into buf0
      if (r < VP) {
        const uint4* s4 = (const uint4*)(ATi + r * VP + h * 16);
        uint4* d4 = (uint4*)(apan + r * 40 + h * 16);
        d4[0] = s4[0];
        d4[1] = s4[1];
      }
      __syncthreads();  // also orders prior xT_s/z1T_s writes vs reads below

      for (int ks = 0; ks < 7; ++ks) {
        int cur = ks & 1;
        uint4 pre0, pre1;
        bool dopre = (ks + 1 < 7) && (r < VP);
        if (dopre) {  // issue next K-panel loads early (L2-resident)
          const uint4* s4 = (const uint4*)(ATi + r * VP + (ks + 1) * 32 + h * 16);
          pre0 = s4[0];
          pre1 = s4[1];
        }
        s16x8 bfrag[2];
#pragma unroll
        for (int nt = 0; nt < 2; ++nt) {
          int col = wn * 32 + nt * 16 + lane15;
          bfrag[nt] = *(const s16x8*)(bsrc + (size_t)col * VP + ks * 32 + lgrp * 8);
        }
#pragma unroll
        for (int mt = 0; mt < 7; ++mt) {
          int row = wm * 112 + mt * 16 + lane15;
          s16x8 afrag = *(const s16x8*)(apan + cur * 8960 + row * 40 + lgrp * 8);
          asm("v_mfma_f32_16x16x32_bf16 %0, %1, %2, %0"
              : "+v"(acc[mt * 2 + 0])
              : "v"(afrag), "v"(bfrag[0]));
          asm("v_mfma_f32_16x16x32_bf16 %0, %1, %2, %0"
              : "+v"(acc[mt * 2 + 1])
              : "v"(afrag), "v"(bfrag[1]));
        }
        if (dopre) {  // write next panel late (hidden under MFMAs)
          uint4* d4 = (uint4*)(apan + ((ks + 1) & 1) * 8960 + r * 40 + h * 16);
          d4[0] = pre0;
          d4[1] = pre1;
        }
        __syncthreads();
      }

      // epilogue: global z store (+ transposed LDS copy for hop2's B operand)
      int slot = 2 * ii + hop;
      u16* zg = zbuf + (size_t)slot * ((size_t)NC * VL) + (size_t)nc * VL;
#pragma unroll
      for (int mt = 0; mt < 7; ++mt) {
#pragma unroll
        for (int nt = 0; nt < 2; ++nt) {
          f32x4 a = acc[mt * 2 + nt];
          int col = wn * 32 + nt * 16 + lane15;       // l
          int wb = wm * 112 + mt * 16 + lgrp * 4;     // w base (4 consecutive)
          u16 u0 = f2bf(a.x), u1 = f2bf(a.y), u2 = f2bf(a.z), u3 = f2bf(a.w);
          if (hop == 0) {
            uint2 pk = make_uint2((u32)u0 | ((u32)u1 << 16),
                                  (u32)u2 | ((u32)u3 << 16));
            *(uint2*)(z1T_s + (size_t)col * VP + wb) = pk;
          }
          if (wb + 0 < VDIM) zg[(wb + 0) * LDIM + col] = u0;
          if (wb + 1 < VDIM) zg[(wb + 1) * LDIM + col] = u1;
          if (wb + 2 < VDIM) zg[(wb + 2) * LDIM + col] = u2;
          if (wb + 3 < VDIM) zg[(wb + 3) * LDIM + col] = u3;
        }
      }
      // next hop's pre-K-loop barrier orders z1T_s writes vs its reads
    }
  }
}

// ---------------- channel mix: out = b + W0*x + sum_g Wg*z_g ----------------
// mode 0: init bias + f32 x-group; mode 1: accumulate into existing out
__global__ __launch_bounds__(256, 4) void k_mix(const float* __restrict__ x,
                                                const u16* __restrict__ zb,
                                                const float* __restrict__ WT,
                                                const float* __restrict__ bias,
                                                float* __restrict__ out,
                                                int nz, int wk0, int mode) {
  int p = blockIdx.x * 256 + threadIdx.x;  // < NPOINT
  int n = p / VL;
  int rem = p - n * VL;
  float* op = out + (size_t)n * 32 * VL + rem;
  float acc[32];
  if (mode == 0) {
#pragma unroll
    for (int o = 0; o < 32; ++o) acc[o] = bias[o];
    const float* xp = x + (size_t)n * 32 * VL + rem;
    for (int c = 0; c < 32; ++c) {
      float inp = xp[(size_t)c * VL];
      const float* wv = WT + c * 32;  // wave-uniform -> scalar loads
#pragma unroll
      for (int o = 0; o < 32; ++o) acc[o] += wv[o] * inp;
    }
  } else {
#pragma unroll
    for (int o = 0; o < 32; ++o) acc[o] = op[(size_t)o * VL];
  }
  for (int g = 0; g < nz; ++g) {
    const u16* zp = zb + ((size_t)g * NC + (size_t)n * 32) * VL + rem;
    const float* wg = WT + (wk0 + g * 32) * 32;
    for (int c = 0; c < 32; ++c) {
      float inp = bf2f(zp[(size_t)c * VL]);
      const float* wv = wg + c * 32;
#pragma unroll
      for (int o = 0; o < 32; ++o) acc[o] += wv[o] * inp;
    }
  }
#pragma unroll
  for (int o = 0; o < 32; ++o) op[(size_t)o * VL] = acc[o];
}

extern "C" void kernel_launch(void* const* d_in, const int* in_sizes, int n_in,
                              void* d_out, int out_size, void* d_ws, size_t ws_size,
                              hipStream_t stream) {
  const float* x = (const float*)d_in[0];
  const float* A0 = (const float*)d_in[1];
  const float* A1 = (const float*)d_in[2];
  const float* A2 = (const float*)d_in[3];
  const float* W = (const float*)d_in[4];
  const float* b = (const float*)d_in[5];
  float* out = (float*)d_out;

  const size_t xT_sz = (size_t)NC * 128 * VP * 2;  // 58,720,256
  const size_t AT_sz = (size_t)3 * VP * VP * 2;    // 301,056
  const size_t WT_sz = (size_t)VP * 32 * 4;        // 28,672
  const size_t slot_sz = (size_t)NC * VL * 2;      // 54,263,808

  char* wp = (char*)d_ws;
  u16* xT = (u16*)wp; wp += (xT_sz + 255) & ~(size_t)255;
  u16* AT = (u16*)wp; wp += (AT_sz + 255) & ~(size_t)255;
  float* WT = (float*)wp; wp += (WT_sz + 255) & ~(size_t)255;
  u16* zbuf = (u16*)wp;
  size_t base = (size_t)(wp - (char*)d_ws);
  bool bigws = ws_size >= base + 6 * slot_sz;

  k_prep<<<616, 256, 0, stream>>>(A0, A1, A2, W, AT, WT);
  k_xt<<<NC, 256, 0, stream>>>(x, xT);
  if (bigws) {
    k_hops<<<NC, 512, 0, stream>>>(xT, AT, zbuf, 0, 3);
    k_mix<<<NPOINT / 256, 256, 0, stream>>>(x, zbuf, WT, b, out, 6, 32, 0);
  } else {
    // low-workspace path: 2 z slots, accumulate per A-matrix
    k_mix<<<NPOINT / 256, 256, 0, stream>>>(x, nullptr, WT, b, out, 0, 32, 0);
    for (int i = 0; i < 3; ++i) {
      k_hops<<<NC, 512, 0, stream>>>(xT, AT, zbuf, i, 1);
      k_mix<<<NPOINT / 256, 256, 0, stream>>>(nullptr, zbuf, WT, nullptr, out, 2,
                                              (1 + 2 * i) * 32, 1);
    }
  }
}